// Round 3
// baseline (1254.427 us; speedup 1.0000x reference)
//
#include <hip/hip_runtime.h>

#define HDIM 128   // hidden = HEADS*D = 2*64

__device__ __forceinline__ float b2f(unsigned short u){
  return __uint_as_float(((unsigned int)u) << 16);
}
__device__ __forceinline__ unsigned short f2b(float f){
  unsigned int x = __float_as_uint(f);
  x += 0x7fffu + ((x >> 16) & 1u);           // round-to-nearest-even
  return (unsigned short)(x >> 16);
}

// ---------------- dtype sniff: even-indexed ushorts of a bf16 buffer are values
// (|v| in [1e-4,50] ~99% for randn); of an fp32 buffer they are low mantissa
// halves (log-uniform garbage, ~7% in range). flag=1 -> fp32 inputs.
__global__ void detect_kernel(const unsigned short* __restrict__ x, int* __restrict__ flag){
  const int tid = threadIdx.x;               // single block of 256
  int cnt = 0, tot = 0;
  for (int i = tid * 2; i < 4096; i += 512){ // 2048 even indices
    float v = fabsf(b2f(x[i]));
    tot++;
    if (v > 1e-4f && v < 50.f) cnt++;
  }
  __shared__ int s_cnt[256], s_tot[256];
  s_cnt[tid] = cnt; s_tot[tid] = tot;
  __syncthreads();
  for (int o = 128; o > 0; o >>= 1){
    if (tid < o){ s_cnt[tid] += s_cnt[tid + o]; s_tot[tid] += s_tot[tid + o]; }
    __syncthreads();
  }
  if (tid == 0) flag[0] = (s_cnt[0] * 2 < s_tot[0]) ? 1 : 0;
}

// ---------------- convert one tensor into canonical bf16 (flag-aware source read)
__global__ void cvt_kernel(const void* __restrict__ src, unsigned short* __restrict__ dst,
                           int n, const int* __restrict__ flag){
  int t = blockIdx.x * 256 + threadIdx.x;
  if (t >= n) return;
  if (*flag) dst[t] = f2b(((const float*)src)[t]);
  else       dst[t] = ((const unsigned short*)src)[t];
}

// canonical params layout (ushort offsets into P):
//  Wp_user@0(8192)  Wp_item@8192(16384)  Wl@24576(65536)  Wr@90112(65536)
//  bl@155648(512)   br@156160(512)       att@156672(512)  bias@157184(512)
//  bp_user@157696(128)  bp_item@157824(128)   total 157952
#define P_WPU 0
#define P_WPI 8192
#define P_WL  24576
#define P_WR  90112
#define P_BL  155648
#define P_BR  156160
#define P_ATT 156672
#define P_BIA 157184
#define P_BPU 157696
#define P_BPI 157824
#define P_TOT 157952

// ---------------- prep: compose layer-0 weights  Wc = Wp @ W  (+ bp @ W + b), bf16 out
// jobs: 0: Wp_user@Wl[0,0] (64x128)   1: Wp_user@Wr[0,1] (64x128)
//       2: Wp_item@Wl[0,1] (128x128)  3: Wp_item@Wr[0,0] (128x128)
// Wc layout: [0:8192) job0, [8192:16384) job1, [16384:32768) job2,
//            [32768:49152) job3, [49152:49664) 4x128 composed biases
__global__ void prep_weights_kernel(const unsigned short* __restrict__ P,
                                    unsigned short* __restrict__ Wc)
{
  const int t = blockIdx.x * 256 + threadIdx.x;
  if (t >= 49664) return;
  const unsigned short* Wl = P + P_WL;
  const unsigned short* Wr = P + P_WR;
  const unsigned short* Bm[4] = { Wl, Wr + 16384, Wl + 16384, Wr };
  const unsigned short* Av[4] = { P + P_WPU, P + P_WPU, P + P_WPI, P + P_WPI };
  const unsigned short* bv[4] = { P + P_BPU, P + P_BPU, P + P_BPI, P + P_BPI };
  const unsigned short* bo[4] = { P + P_BL, P + P_BR + 128, P + P_BL + 128, P + P_BR };
  if (t < 49152){
    int job, base;
    if (t < 8192)       { job = 0; base = 0; }
    else if (t < 16384) { job = 1; base = 8192; }
    else if (t < 32768) { job = 2; base = 16384; }
    else                { job = 3; base = 32768; }
    const int local = t - base;
    const int k = local >> 7, n = local & 127;
    const unsigned short* A = Av[job] + (size_t)k * 128;
    const unsigned short* B = Bm[job];
    float s = 0.f;
    #pragma unroll 4
    for (int h = 0; h < 128; h++) s = fmaf(b2f(A[h]), b2f(B[h * 128 + n]), s);
    Wc[t] = f2b(s);
  } else {
    const int local = t - 49152;
    const int job = local >> 7, n = local & 127;
    const unsigned short* B = Bm[job];
    float s = b2f(bo[job][n]);
    for (int h = 0; h < 128; h++) s = fmaf(b2f(bv[job][h]), b2f(B[h * 128 + n]), s);
    Wc[t] = f2b(s);
  }
}

// ---------------- Linear: Y[M,128] = X[M,K] @ W[K,128] + B; X bf16 or fp32, W/B/Y bf16
template<int K>
__launch_bounds__(256)
__global__ void linear_kernel(const void* __restrict__ Xvoid,
                              const unsigned short* __restrict__ W,
                              const unsigned short* __restrict__ B,
                              unsigned short* __restrict__ Y,
                              const int* __restrict__ flag, int use_flag)
{
  __shared__ alignas(16) unsigned short Ws[K * HDIM];
  __shared__ alignas(16) float Xs[K * 32];      // [k][r] transposed
  const int tid = threadIdx.x;
  const size_t rowBase = (size_t)blockIdx.x * 32;
  const bool f32 = use_flag && (*flag != 0);

  for (int i = tid; i < K * HDIM / 8; i += 256)
    ((uint4*)Ws)[i] = ((const uint4*)W)[i];

  if (f32){
    const float4* Xv = (const float4*)((const float*)Xvoid + rowBase * K);
    for (int i = tid; i < 32 * K / 8; i += 256){
      float4 a = Xv[2 * i], b = Xv[2 * i + 1];
      int flat = i * 8;
      int r = flat / K, c = flat % K;
      const float vals[8] = {a.x, a.y, a.z, a.w, b.x, b.y, b.z, b.w};
      #pragma unroll
      for (int j = 0; j < 8; j++) Xs[(c + j) * 32 + r] = vals[j];
    }
  } else {
    const uint4* Xv = (const uint4*)((const unsigned short*)Xvoid + rowBase * K);
    for (int i = tid; i < 32 * K / 8; i += 256){
      uint4 v = Xv[i];
      int flat = i * 8;
      int r = flat / K, c = flat % K;
      const unsigned short* u = (const unsigned short*)&v;
      #pragma unroll
      for (int j = 0; j < 8; j++) Xs[(c + j) * 32 + r] = b2f(u[j]);
    }
  }
  __syncthreads();

  const int tx = tid & 31, ty = tid >> 5;
  const int n0 = tx * 4, r0 = ty * 4;           // 4 cols x 4 rows per thread
  float acc[4][4] = {};
  #pragma unroll 2
  for (int k = 0; k < K; k++){
    const float4 xv = *(const float4*)&Xs[k * 32 + r0];
    const uint2 wv = *(const uint2*)&Ws[k * HDIM + n0];
    float wj[4];
    wj[0] = __uint_as_float(wv.x << 16);
    wj[1] = __uint_as_float(wv.x & 0xffff0000u);
    wj[2] = __uint_as_float(wv.y << 16);
    wj[3] = __uint_as_float(wv.y & 0xffff0000u);
    const float xi[4] = {xv.x, xv.y, xv.z, xv.w};
    #pragma unroll
    for (int i = 0; i < 4; i++)
      #pragma unroll
      for (int j = 0; j < 4; j++)
        acc[i][j] = fmaf(xi[i], wj[j], acc[i][j]);
  }
  float bj[4];
  #pragma unroll
  for (int j = 0; j < 4; j++) bj[j] = b2f(B[n0 + j]);
  #pragma unroll
  for (int i = 0; i < 4; i++){
    ushort4 o;
    o.x = f2b(acc[i][0] + bj[0]);
    o.y = f2b(acc[i][1] + bj[1]);
    o.z = f2b(acc[i][2] + bj[2]);
    o.w = f2b(acc[i][3] + bj[3]);
    *(ushort4*)&Y[(rowBase + r0 + i) * HDIM + n0] = o;
  }
}

// ---------------- E1: logits[e,h] = a[h]·leakyrelu(xl[src,h,:]+xr[dst,h,:]); amax = seg-max
__global__ void edge_logits_kernel(const unsigned short* __restrict__ xl,
                                   const unsigned short* __restrict__ xr,
                                   const int* __restrict__ src,
                                   const int* __restrict__ dst,
                                   const unsigned short* __restrict__ att,  // [2][64] bf16
                                   float* __restrict__ logits,              // [E,2]
                                   float* __restrict__ amax,                // [Nd,2], init 0xff sentinel
                                   int E)
{
  __shared__ alignas(16) float a_s[HDIM];
  if (threadIdx.x < HDIM) a_s[threadIdx.x] = b2f(att[threadIdx.x]);
  __syncthreads();
  int t = blockIdx.x * 256 + threadIdx.x;
  if (t >= 2 * E) return;
  const int e = t >> 1, h = t & 1;
  const int s = src[e], d = dst[e];
  const uint4* pl = (const uint4*)(xl + (size_t)s * HDIM + h * 64);
  const uint4* pr = (const uint4*)(xr + (size_t)d * HDIM + h * 64);
  float sum = 0.f;
  #pragma unroll
  for (int j = 0; j < 8; j++){
    uint4 lv = pl[j], rv = pr[j];
    const unsigned short* lu = (const unsigned short*)&lv;
    const unsigned short* ru = (const unsigned short*)&rv;
    float4 a0 = ((const float4*)a_s)[(h << 4) + j * 2];
    float4 a1 = ((const float4*)a_s)[(h << 4) + j * 2 + 1];
    const float aa[8] = {a0.x, a0.y, a0.z, a0.w, a1.x, a1.y, a1.z, a1.w};
    #pragma unroll
    for (int i = 0; i < 8; i++){
      float x = b2f(lu[i]) + b2f(ru[i]);
      x = fmaxf(x, 0.2f * x);                // leaky_relu(x, 0.2)
      sum = fmaf(aa[i], x, sum);
    }
  }
  logits[t] = sum;
  float* addr = &amax[(size_t)d * 2 + h];
  // float atomic max via monotone int/uint views; branch on SIGN BIT so -0.0
  // goes through the uint path (sentinel 0xffffffff works for both paths)
  const unsigned int sb = __float_as_uint(sum);
  if ((int)sb >= 0) atomicMax((int*)addr, (int)sb);
  else              atomicMin((unsigned int*)addr, sb);
}

// ---------------- E2: p = exp(logit - amax[dst]); denom = seg-sum(p). In-place over logits.
__global__ void edge_softmax_kernel(const int* __restrict__ dst,
                                    float* __restrict__ logits,     // in: logits, out: p
                                    const float* __restrict__ amax,
                                    float* __restrict__ denom,      // init 0
                                    int E)
{
  int t = blockIdx.x * 256 + threadIdx.x;
  if (t >= 2 * E) return;
  const int e = t >> 1, h = t & 1;
  const int d = dst[e];
  float p = __expf(logits[t] - amax[(size_t)d * 2 + h]);
  logits[t] = p;
  atomicAdd(&denom[(size_t)d * 2 + h], p);
}

// ---------------- E3: acc[dst, c] += p[e, c>>6] * xl[src, c]
__global__ void edge_aggregate_kernel(const unsigned short* __restrict__ xl,
                                      const int* __restrict__ src,
                                      const int* __restrict__ dst,
                                      const float* __restrict__ p,   // [E,2]
                                      float* __restrict__ acc,       // [Nd,128], init 0
                                      int E)
{
  int t = blockIdx.x * 256 + threadIdx.x;    // e*128 + c, max 32e6 < 2^31
  if (t >= E * HDIM) return;
  const int e = t >> 7, c = t & 127;
  const int s = src[e], d = dst[e];
  const float v = p[e * 2 + (c >> 6)] * b2f(xl[(size_t)s * HDIM + c]);
  atomicAdd(&acc[(size_t)d * HDIM + c], v);
}

// ---------------- finalize: v = acc/(denom+1e-16) + bias, opt relu; store bf16 or fp32
__global__ void finalize_kernel(const float* __restrict__ acc,
                                const float* __restrict__ denom,
                                const unsigned short* __restrict__ bias,
                                void* __restrict__ out, size_t elem_off,
                                int N, int do_relu,
                                const int* __restrict__ flag, int use_flag)
{
  int t = blockIdx.x * 256 + threadIdx.x;
  if (t >= N * HDIM) return;
  const int n = t >> 7, c = t & 127;
  float v = acc[t] / (denom[(size_t)n * 2 + (c >> 6)] + 1e-16f) + b2f(bias[c]);
  if (do_relu) v = fmaxf(v, 0.f);
  if (use_flag && (*flag != 0)) ((float*)out)[elem_off + t] = v;
  else                          ((unsigned short*)out)[elem_off + t] = f2b(v);
}

extern "C" void kernel_launch(void* const* d_in, const int* in_sizes, int n_in,
                              void* d_out, int out_size, void* d_ws, size_t ws_size,
                              hipStream_t stream)
{
  const int* esrc = (const int*)d_in[12];
  const int* edst = (const int*)d_in[13];

  const int NU = in_sizes[0] / 64;    // 100000
  const int NI = in_sizes[1] / 128;   // 20000
  const int E  = in_sizes[12];        // 250000
  const size_t fu = (size_t)NU * HDIM, fi = (size_t)NI * HDIM;

  // ---- workspace carve (~86 MB): small buffers first, big aliased ACC last
  char* w = (char*)d_ws;
  int*   flag   = (int*)w;            w += 256;
  float* logits = (float*)w;          w += (size_t)E * 2 * 4;      //  2.00 MB
  float* amax   = (float*)w;          w += (size_t)NU * 2 * 4;     //  0.80 MB
  float* denom  = (float*)w;          w += (size_t)NU * 2 * 4;     //  0.80 MB
  unsigned short* Wc = (unsigned short*)w; w += 49664 * 2 + 128;   //  0.10 MB
  unsigned short* P  = (unsigned short*)w; w += P_TOT * 2 + 96;    //  0.32 MB (pad->16B)
  unsigned short* xrU = (unsigned short*)w; w += fu * 2;           // 25.6 MB
  unsigned short* xlI = (unsigned short*)w; w += fi * 2;           //  5.12 MB
  char* ACC = w;                      w += fu * 4;                 // 51.2 MB
  unsigned short* xlU = (unsigned short*)ACC;                 // [0, 25.6MB)
  unsigned short* xrI = (unsigned short*)(ACC + fu * 2);      // [25.6, 30.72MB)
  float* accI = (float*)(ACC + fu * 2 + fi * 2);              // [30.72, 40.96MB)
  float* accU = (float*)ACC;
  (void)ws_size; (void)n_in; (void)out_size;

  // staging of layer-0 activations is ALWAYS bf16 in d_out's low bytes; the
  // final store format follows the sniffed flag. Byte-disjointness of fp32
  // final writes vs staging reads was verified for both dtype cases.
  unsigned short* stage_zu = (unsigned short*)d_out;
  unsigned short* stage_zi = (unsigned short*)d_out + fu;

  const int gE2 = (2 * E + 255) / 256;
  const int gE128 = (E * HDIM + 255) / 256;

  // ---- dtype sniff + canonical bf16 params
  detect_kernel<<<1, 256, 0, stream>>>((const unsigned short*)d_in[0], flag);
  struct { int src; int off; int n; } segs[10] = {
    {2, P_WPU, 8192}, {4, P_WPI, 16384}, {6, P_WL, 65536}, {8, P_WR, 65536},
    {7, P_BL, 512}, {9, P_BR, 512}, {10, P_ATT, 512}, {11, P_BIA, 512},
    {3, P_BPU, 128}, {5, P_BPI, 128}
  };
  for (int i = 0; i < 10; i++)
    cvt_kernel<<<(segs[i].n + 255) / 256, 256, 0, stream>>>(
        d_in[segs[i].src], P + segs[i].off, segs[i].n, flag);

  // ---- compose layer-0 weights (projection folded in; no nonlinearity between)
  prep_weights_kernel<<<(49664 + 255) / 256, 256, 0, stream>>>(P, Wc);
  const unsigned short* cWlU0 = Wc;                 // [64,128]
  const unsigned short* cWrU1 = Wc + 8192;          // [64,128]
  const unsigned short* cWlI1 = Wc + 16384;         // [128,128]
  const unsigned short* cWrI0 = Wc + 32768;         // [128,128]
  const unsigned short* cb0 = Wc + 49152;
  const unsigned short* cb1 = Wc + 49152 + 128;
  const unsigned short* cb2 = Wc + 49152 + 256;
  const unsigned short* cb3 = Wc + 49152 + 384;

  for (int l = 0; l < 2; l++){
    // ---- all four transforms first
    if (l == 0){
      linear_kernel<64><<<NU / 32, 256, 0, stream>>>(d_in[0], cWlU0, cb0, xlU, flag, 1);
      linear_kernel<64><<<NU / 32, 256, 0, stream>>>(d_in[0], cWrU1, cb1, xrU, flag, 1);
      linear_kernel<128><<<NI / 32, 256, 0, stream>>>(d_in[1], cWlI1, cb2, xlI, flag, 1);
      linear_kernel<128><<<NI / 32, 256, 0, stream>>>(d_in[1], cWrI0, cb3, xrI, flag, 1);
    } else {
      linear_kernel<128><<<NU / 32, 256, 0, stream>>>(stage_zu, P + P_WL + 2 * 16384, P + P_BL + 256, xlU, flag, 0);
      linear_kernel<128><<<NU / 32, 256, 0, stream>>>(stage_zu, P + P_WR + 3 * 16384, P + P_BR + 384, xrU, flag, 0);
      linear_kernel<128><<<NI / 32, 256, 0, stream>>>(stage_zi, P + P_WL + 3 * 16384, P + P_BL + 384, xlI, flag, 0);
      linear_kernel<128><<<NI / 32, 256, 0, stream>>>(stage_zi, P + P_WR + 2 * 16384, P + P_BR + 256, xrI, flag, 0);
    }
    const int relu = (l == 0);
    const int final_store = (l == 1);   // layer-0 stores bf16 staging; layer-1 flag-dependent
    void* outU_dst = final_store ? d_out : (void*)stage_zu;   // zu at elem_off 0
    void* outI_dst = final_store ? d_out : (void*)stage_zu;   // zi at elem_off fu
    const unsigned short* att0  = P + P_ATT + (l * 2 + 0) * HDIM;
    const unsigned short* att1  = P + P_ATT + (l * 2 + 1) * HDIM;
    const unsigned short* bias0 = P + P_BIA + (l * 2 + 0) * HDIM;
    const unsigned short* bias1 = P + P_BIA + (l * 2 + 1) * HDIM;

    // ===== rel 0: user -> item (src=esrc, dst=edst, Nd=NI)
    hipMemsetAsync(amax, 0xff, (size_t)NI * 2 * 4, stream);
    hipMemsetAsync(denom, 0, (size_t)NI * 2 * 4, stream);
    edge_logits_kernel<<<gE2, 256, 0, stream>>>(xlU, xrI, esrc, edst, att0, logits, amax, E);
    edge_softmax_kernel<<<gE2, 256, 0, stream>>>(edst, logits, amax, denom, E);
    hipMemsetAsync(accI, 0, fi * 4, stream);   // xrI dead after E1; xlU disjoint
    edge_aggregate_kernel<<<gE128, 256, 0, stream>>>(xlU, esrc, edst, logits, accI, E);
    finalize_kernel<<<(int)((fi + 255) / 256), 256, 0, stream>>>(
        accI, denom, bias0, outI_dst, fu, NI, relu, flag, final_store);

    // ===== rel 1: item -> user (src=edst, dst=esrc, Nd=NU)
    hipMemsetAsync(amax, 0xff, (size_t)NU * 2 * 4, stream);
    hipMemsetAsync(denom, 0, (size_t)NU * 2 * 4, stream);
    edge_logits_kernel<<<gE2, 256, 0, stream>>>(xlI, xrU, edst, esrc, att1, logits, amax, E);
    edge_softmax_kernel<<<gE2, 256, 0, stream>>>(esrc, logits, amax, denom, E);
    hipMemsetAsync(accU, 0, fu * 4, stream);   // xlU/xrI/accI all dead now
    edge_aggregate_kernel<<<gE128, 256, 0, stream>>>(xlI, edst, esrc, logits, accU, E);
    finalize_kernel<<<(int)((fu + 255) / 256), 256, 0, stream>>>(
        accU, denom, bias1, outU_dst, 0, NU, relu, flag, final_store);
  }
}

// Round 4
// 640.091 us; speedup vs baseline: 1.9598x; 1.9598x over previous
//
#include <hip/hip_runtime.h>

#define HDIM 128   // hidden = HEADS*D = 2*64

__device__ __forceinline__ float b2f(unsigned short u){
  return __uint_as_float(((unsigned int)u) << 16);
}
__device__ __forceinline__ unsigned short f2b(float f){
  unsigned int x = __float_as_uint(f);
  x += 0x7fffu + ((x >> 16) & 1u);           // round-to-nearest-even
  return (unsigned short)(x >> 16);
}

// ---------------- dtype sniff: even-indexed ushorts of a bf16 buffer are values;
// of an fp32 buffer they are mantissa halves (~7% in-range). flag=1 -> fp32 inputs.
__global__ void detect_kernel(const unsigned short* __restrict__ x, int* __restrict__ flag){
  const int tid = threadIdx.x;               // single block of 256
  int cnt = 0, tot = 0;
  for (int i = tid * 2; i < 4096; i += 512){
    float v = fabsf(b2f(x[i]));
    tot++;
    if (v > 1e-4f && v < 50.f) cnt++;
  }
  __shared__ int s_cnt[256], s_tot[256];
  s_cnt[tid] = cnt; s_tot[tid] = tot;
  __syncthreads();
  for (int o = 128; o > 0; o >>= 1){
    if (tid < o){ s_cnt[tid] += s_cnt[tid + o]; s_tot[tid] += s_tot[tid + o]; }
    __syncthreads();
  }
  if (tid == 0) flag[0] = (s_cnt[0] * 2 < s_tot[0]) ? 1 : 0;
}

// ---------------- convert one tensor into canonical bf16 (flag-aware source read)
__global__ void cvt_kernel(const void* __restrict__ src, unsigned short* __restrict__ dst,
                           int n, const int* __restrict__ flag){
  int t = blockIdx.x * 256 + threadIdx.x;
  if (t >= n) return;
  if (*flag) dst[t] = f2b(((const float*)src)[t]);
  else       dst[t] = ((const unsigned short*)src)[t];
}

// canonical params layout (ushort offsets into P)
#define P_WPU 0
#define P_WPI 8192
#define P_WL  24576
#define P_WR  90112
#define P_BL  155648
#define P_BR  156160
#define P_ATT 156672
#define P_BIA 157184
#define P_BPU 157696
#define P_BPI 157824
#define P_TOT 157952

// ---------------- prep: compose layer-0 weights  Wc = Wp @ W  (+ bp @ W + b), bf16 out
__global__ void prep_weights_kernel(const unsigned short* __restrict__ P,
                                    unsigned short* __restrict__ Wc)
{
  const int t = blockIdx.x * 256 + threadIdx.x;
  if (t >= 49664) return;
  const unsigned short* Wl = P + P_WL;
  const unsigned short* Wr = P + P_WR;
  const unsigned short* Bm[4] = { Wl, Wr + 16384, Wl + 16384, Wr };
  const unsigned short* Av[4] = { P + P_WPU, P + P_WPU, P + P_WPI, P + P_WPI };
  const unsigned short* bv[4] = { P + P_BPU, P + P_BPU, P + P_BPI, P + P_BPI };
  const unsigned short* bo[4] = { P + P_BL, P + P_BR + 128, P + P_BL + 128, P + P_BR };
  if (t < 49152){
    int job, base;
    if (t < 8192)       { job = 0; base = 0; }
    else if (t < 16384) { job = 1; base = 8192; }
    else if (t < 32768) { job = 2; base = 16384; }
    else                { job = 3; base = 32768; }
    const int local = t - base;
    const int k = local >> 7, n = local & 127;
    const unsigned short* A = Av[job] + (size_t)k * 128;
    const unsigned short* B = Bm[job];
    float s = 0.f;
    #pragma unroll 4
    for (int h = 0; h < 128; h++) s = fmaf(b2f(A[h]), b2f(B[h * 128 + n]), s);
    Wc[t] = f2b(s);
  } else {
    const int local = t - 49152;
    const int job = local >> 7, n = local & 127;
    const unsigned short* B = Bm[job];
    float s = b2f(bo[job][n]);
    for (int h = 0; h < 128; h++) s = fmaf(b2f(bv[job][h]), b2f(B[h * 128 + n]), s);
    Wc[t] = f2b(s);
  }
}

// ---------------- Linear: Y[M,128] = X[M,K] @ W[K,128] + B; X bf16 or fp32, W/B/Y bf16
template<int K>
__launch_bounds__(256)
__global__ void linear_kernel(const void* __restrict__ Xvoid,
                              const unsigned short* __restrict__ W,
                              const unsigned short* __restrict__ B,
                              unsigned short* __restrict__ Y,
                              const int* __restrict__ flag, int use_flag)
{
  __shared__ alignas(16) unsigned short Ws[K * HDIM];
  __shared__ alignas(16) float Xs[K * 32];      // [k][r] transposed
  const int tid = threadIdx.x;
  const size_t rowBase = (size_t)blockIdx.x * 32;
  const bool f32 = use_flag && (*flag != 0);

  for (int i = tid; i < K * HDIM / 8; i += 256)
    ((uint4*)Ws)[i] = ((const uint4*)W)[i];

  if (f32){
    const float4* Xv = (const float4*)((const float*)Xvoid + rowBase * K);
    for (int i = tid; i < 32 * K / 8; i += 256){
      float4 a = Xv[2 * i], b = Xv[2 * i + 1];
      int flat = i * 8;
      int r = flat / K, c = flat % K;
      const float vals[8] = {a.x, a.y, a.z, a.w, b.x, b.y, b.z, b.w};
      #pragma unroll
      for (int j = 0; j < 8; j++) Xs[(c + j) * 32 + r] = vals[j];
    }
  } else {
    const uint4* Xv = (const uint4*)((const unsigned short*)Xvoid + rowBase * K);
    for (int i = tid; i < 32 * K / 8; i += 256){
      uint4 v = Xv[i];
      int flat = i * 8;
      int r = flat / K, c = flat % K;
      const unsigned short* u = (const unsigned short*)&v;
      #pragma unroll
      for (int j = 0; j < 8; j++) Xs[(c + j) * 32 + r] = b2f(u[j]);
    }
  }
  __syncthreads();

  const int tx = tid & 31, ty = tid >> 5;
  const int n0 = tx * 4, r0 = ty * 4;
  float acc[4][4] = {};
  #pragma unroll 2
  for (int k = 0; k < K; k++){
    const float4 xv = *(const float4*)&Xs[k * 32 + r0];
    const uint2 wv = *(const uint2*)&Ws[k * HDIM + n0];
    float wj[4];
    wj[0] = __uint_as_float(wv.x << 16);
    wj[1] = __uint_as_float(wv.x & 0xffff0000u);
    wj[2] = __uint_as_float(wv.y << 16);
    wj[3] = __uint_as_float(wv.y & 0xffff0000u);
    const float xi[4] = {xv.x, xv.y, xv.z, xv.w};
    #pragma unroll
    for (int i = 0; i < 4; i++)
      #pragma unroll
      for (int j = 0; j < 4; j++)
        acc[i][j] = fmaf(xi[i], wj[j], acc[i][j]);
  }
  float bj[4];
  #pragma unroll
  for (int j = 0; j < 4; j++) bj[j] = b2f(B[n0 + j]);
  #pragma unroll
  for (int i = 0; i < 4; i++){
    ushort4 o;
    o.x = f2b(acc[i][0] + bj[0]);
    o.y = f2b(acc[i][1] + bj[1]);
    o.z = f2b(acc[i][2] + bj[2]);
    o.w = f2b(acc[i][3] + bj[3]);
    *(ushort4*)&Y[(rowBase + r0 + i) * HDIM + n0] = o;
  }
}

// ================= CSR build =================
__global__ void count_kernel(const int* __restrict__ dst, int* __restrict__ deg, int E){
  int t = blockIdx.x * 256 + threadIdx.x;
  if (t < E) atomicAdd(&deg[dst[t]], 1);
}

// scan1: per-block (2048 elems) exclusive scan into rowptr, block total to blksum
__global__ void scan_block_kernel(const int* __restrict__ deg, int* __restrict__ rowptr,
                                  int* __restrict__ blksum, int Nd){
  __shared__ int s[256];
  const int tid = threadIdx.x;
  const int base = blockIdx.x * 2048 + tid * 8;
  int v[8]; int tot = 0;
  #pragma unroll
  for (int j = 0; j < 8; j++){
    int idx = base + j;
    v[j] = (idx < Nd) ? deg[idx] : 0;
    tot += v[j];
  }
  s[tid] = tot;
  __syncthreads();
  for (int off = 1; off < 256; off <<= 1){
    int add = (tid >= off) ? s[tid - off] : 0;
    __syncthreads();
    s[tid] += add;
    __syncthreads();
  }
  int run = s[tid] - tot;     // exclusive prefix of this thread's chunk
  #pragma unroll
  for (int j = 0; j < 8; j++){
    int idx = base + j;
    if (idx < Nd) rowptr[idx] = run;
    run += v[j];
  }
  if (tid == 255) blksum[blockIdx.x] = s[255];
}

// scan2: single wave scans block sums (B <= 64) to exclusive
__global__ void scan_top_kernel(int* __restrict__ blksum, int B){
  const int tid = threadIdx.x;   // 64 threads
  int v = (tid < B) ? blksum[tid] : 0;
  const int orig = v;
  #pragma unroll
  for (int off = 1; off < 64; off <<= 1){
    int u = __shfl_up(v, off, 64);
    if (tid >= off) v += u;
  }
  if (tid < B) blksum[tid] = v - orig;
}

// scan3: add block offsets; also set rowptr[Nd] = E
__global__ void scan_add_kernel(int* __restrict__ rowptr, const int* __restrict__ blksum,
                                int Nd, int E){
  const int base = blockIdx.x * 2048 + threadIdx.x * 8;
  const int add = blksum[blockIdx.x];
  #pragma unroll
  for (int j = 0; j < 8; j++){
    int idx = base + j;
    if (idx < Nd) rowptr[idx] += add;
    else if (idx == Nd) rowptr[idx] = E;
  }
}

__global__ void scatter_kernel(const int* __restrict__ dst, const int* __restrict__ src,
                               int* __restrict__ cursor, int* __restrict__ srcOut, int E){
  int t = blockIdx.x * 256 + threadIdx.x;
  if (t >= E) return;
  int d = dst[t];
  int pos = atomicAdd(&cursor[d], 1);
  srcOut[pos] = src[t];
}

// ================= fused per-destination GATv2 (online softmax) =================
// one wave per dst node: lane holds features {2*lane, 2*lane+1} (head = lane>>5).
__launch_bounds__(256)
__global__ void fused_gat_kernel(const unsigned short* __restrict__ xl,
                                 const unsigned short* __restrict__ xr,
                                 const int* __restrict__ rowptr,
                                 const int* __restrict__ srcArr,
                                 const unsigned short* __restrict__ att,
                                 const unsigned short* __restrict__ bias,
                                 void* __restrict__ out, size_t elem_off,
                                 int Nd, int do_relu,
                                 const int* __restrict__ flag, int final_store)
{
  const int wave = threadIdx.x >> 6, lane = threadIdx.x & 63;
  const int d = blockIdx.x * 4 + wave;
  if (d >= Nd) return;

  const unsigned int rv = ((const unsigned int*)xr)[(size_t)d * 64 + lane];
  const float r0 = b2f((unsigned short)rv), r1 = b2f((unsigned short)(rv >> 16));
  const float a0 = b2f(att[2 * lane]), a1 = b2f(att[2 * lane + 1]);

  const int beg = rowptr[d], end = rowptr[d + 1];
  float m = -INFINITY, srun = 0.f, acc0 = 0.f, acc1 = 0.f;

  for (int e = beg; e < end; e++){
    const int s = srcArr[e];
    const unsigned int xv = ((const unsigned int*)xl)[(size_t)s * 64 + lane];
    const float x0 = b2f((unsigned short)xv), x1 = b2f((unsigned short)(xv >> 16));
    float t0 = x0 + r0; t0 = fmaxf(t0, 0.2f * t0);     // leaky_relu 0.2
    float t1 = x1 + r1; t1 = fmaxf(t1, 0.2f * t1);
    float part = fmaf(a0, t0, a1 * t1);
    // reduce within each 32-lane half (head 0 = lanes 0-31, head 1 = lanes 32-63)
    part += __shfl_xor(part, 1, 64);
    part += __shfl_xor(part, 2, 64);
    part += __shfl_xor(part, 4, 64);
    part += __shfl_xor(part, 8, 64);
    part += __shfl_xor(part, 16, 64);
    // online softmax update
    const float mn = fmaxf(m, part);
    const float sc = __expf(m - mn);
    const float p  = __expf(part - mn);
    srun = fmaf(srun, sc, p);
    acc0 = fmaf(acc0, sc, p * x0);
    acc1 = fmaf(acc1, sc, p * x1);
    m = mn;
  }

  const float inv = 1.f / (srun + 1e-16f);
  float o0 = fmaf(acc0, inv, b2f(bias[2 * lane]));
  float o1 = fmaf(acc1, inv, b2f(bias[2 * lane + 1]));
  if (do_relu){ o0 = fmaxf(o0, 0.f); o1 = fmaxf(o1, 0.f); }
  const size_t idx = elem_off + (size_t)d * HDIM + 2 * lane;   // even
  if (final_store && (*flag != 0)){
    ((float*)out)[idx] = o0;
    ((float*)out)[idx + 1] = o1;
  } else {
    ((unsigned int*)out)[idx >> 1] = (unsigned int)f2b(o0) | ((unsigned int)f2b(o1) << 16);
  }
}

extern "C" void kernel_launch(void* const* d_in, const int* in_sizes, int n_in,
                              void* d_out, int out_size, void* d_ws, size_t ws_size,
                              hipStream_t stream)
{
  const int* esrc = (const int*)d_in[12];
  const int* edst = (const int*)d_in[13];

  const int NU = in_sizes[0] / 64;    // 100000
  const int NI = in_sizes[1] / 128;   // 20000
  const int E  = in_sizes[12];        // 250000
  const size_t fu = (size_t)NU * HDIM, fi = (size_t)NI * HDIM;

  // ---- workspace carve (~66 MB), every region 256B-aligned
  char* w = (char*)d_ws;
  auto carve = [&](size_t bytes){ char* p = w; w += (bytes + 255) & ~(size_t)255; return p; };
  int* flag = (int*)carve(4);
  unsigned short* Wc = (unsigned short*)carve(49664 * 2);
  unsigned short* P  = (unsigned short*)carve((size_t)P_TOT * 2);
  int* rowptrI = (int*)carve(((size_t)NI + 1) * 4);
  int* rowptrU = (int*)carve(((size_t)NU + 1) * 4);
  int* cursI = (int*)carve((size_t)NI * 4);
  int* cursU = (int*)carve((size_t)NU * 4);
  int* blk   = (int*)carve(128 * 4);
  int* srcI  = (int*)carve((size_t)E * 4);   // CSR by item-dst: stores user idx
  int* srcU  = (int*)carve((size_t)E * 4);   // CSR by user-dst: stores item idx
  unsigned short* xlU = (unsigned short*)carve(fu * 2);
  unsigned short* xrU = (unsigned short*)carve(fu * 2);
  unsigned short* xlI = (unsigned short*)carve(fi * 2);
  unsigned short* xrI = (unsigned short*)carve(fi * 2);
  (void)ws_size; (void)n_in; (void)out_size;

  // layer-0 activations stage as bf16 in d_out's low bytes; final store follows flag.
  unsigned short* stage_zu = (unsigned short*)d_out;
  unsigned short* stage_zi = (unsigned short*)d_out + fu;

  const int gE = (E + 255) / 256;

  // ---- dtype sniff + canonical bf16 params
  detect_kernel<<<1, 256, 0, stream>>>((const unsigned short*)d_in[0], flag);
  struct { int src; int off; int n; } segs[10] = {
    {2, P_WPU, 8192}, {4, P_WPI, 16384}, {6, P_WL, 65536}, {8, P_WR, 65536},
    {7, P_BL, 512}, {9, P_BR, 512}, {10, P_ATT, 512}, {11, P_BIA, 512},
    {3, P_BPU, 128}, {5, P_BPI, 128}
  };
  for (int i = 0; i < 10; i++)
    cvt_kernel<<<(segs[i].n + 255) / 256, 256, 0, stream>>>(
        d_in[segs[i].src], P + segs[i].off, segs[i].n, flag);
  prep_weights_kernel<<<(49664 + 255) / 256, 256, 0, stream>>>(P, Wc);

  // ---- CSR build, both directions (edges identical across layers)
  // item-dst CSR
  {
    const int B = (NI + 2047) / 2048;
    hipMemsetAsync(cursI, 0, (size_t)NI * 4, stream);              // cursI doubles as deg
    count_kernel<<<gE, 256, 0, stream>>>(edst, cursI, E);
    scan_block_kernel<<<B, 256, 0, stream>>>(cursI, rowptrI, blk, NI);
    scan_top_kernel<<<1, 64, 0, stream>>>(blk, B);
    scan_add_kernel<<<B, 256, 0, stream>>>(rowptrI, blk, NI, E);
    hipMemcpyAsync(cursI, rowptrI, (size_t)NI * 4, hipMemcpyDeviceToDevice, stream);
    scatter_kernel<<<gE, 256, 0, stream>>>(edst, esrc, cursI, srcI, E);
  }
  // user-dst CSR
  {
    const int B = (NU + 2047) / 2048;
    hipMemsetAsync(cursU, 0, (size_t)NU * 4, stream);
    count_kernel<<<gE, 256, 0, stream>>>(esrc, cursU, E);
    scan_block_kernel<<<B, 256, 0, stream>>>(cursU, rowptrU, blk, NU);
    scan_top_kernel<<<1, 64, 0, stream>>>(blk, B);
    scan_add_kernel<<<B, 256, 0, stream>>>(rowptrU, blk, NU, E);
    hipMemcpyAsync(cursU, rowptrU, (size_t)NU * 4, hipMemcpyDeviceToDevice, stream);
    scatter_kernel<<<gE, 256, 0, stream>>>(esrc, edst, cursU, srcU, E);
  }

  const unsigned short* cWlU0 = Wc;                 // [64,128]
  const unsigned short* cWrU1 = Wc + 8192;          // [64,128]
  const unsigned short* cWlI1 = Wc + 16384;         // [128,128]
  const unsigned short* cWrI0 = Wc + 32768;         // [128,128]
  const unsigned short* cb0 = Wc + 49152;
  const unsigned short* cb1 = Wc + 49152 + 128;
  const unsigned short* cb2 = Wc + 49152 + 256;
  const unsigned short* cb3 = Wc + 49152 + 384;

  for (int l = 0; l < 2; l++){
    if (l == 0){
      linear_kernel<64><<<NU / 32, 256, 0, stream>>>(d_in[0], cWlU0, cb0, xlU, flag, 1);
      linear_kernel<64><<<NU / 32, 256, 0, stream>>>(d_in[0], cWrU1, cb1, xrU, flag, 1);
      linear_kernel<128><<<NI / 32, 256, 0, stream>>>(d_in[1], cWlI1, cb2, xlI, flag, 1);
      linear_kernel<128><<<NI / 32, 256, 0, stream>>>(d_in[1], cWrI0, cb3, xrI, flag, 1);
    } else {
      linear_kernel<128><<<NU / 32, 256, 0, stream>>>(stage_zu, P + P_WL + 2 * 16384, P + P_BL + 256, xlU, flag, 0);
      linear_kernel<128><<<NU / 32, 256, 0, stream>>>(stage_zu, P + P_WR + 3 * 16384, P + P_BR + 384, xrU, flag, 0);
      linear_kernel<128><<<NI / 32, 256, 0, stream>>>(stage_zi, P + P_WL + 3 * 16384, P + P_BL + 384, xlI, flag, 0);
      linear_kernel<128><<<NI / 32, 256, 0, stream>>>(stage_zi, P + P_WR + 2 * 16384, P + P_BR + 256, xrI, flag, 0);
    }
    const int relu = (l == 0);
    const int final_store = (l == 1);
    void* outI_dst = final_store ? d_out : (void*)stage_zu;  // zi at elem_off fu
    void* outU_dst = final_store ? d_out : (void*)stage_zu;  // zu at elem_off 0
    const unsigned short* att0  = P + P_ATT + (l * 2 + 0) * HDIM;
    const unsigned short* att1  = P + P_ATT + (l * 2 + 1) * HDIM;
    const unsigned short* bias0 = P + P_BIA + (l * 2 + 0) * HDIM;
    const unsigned short* bias1 = P + P_BIA + (l * 2 + 1) * HDIM;

    // rel 0: user -> item (dst=item)
    fused_gat_kernel<<<(NI + 3) / 4, 256, 0, stream>>>(
        xlU, xrI, rowptrI, srcI, att0, bias0, outI_dst, fu, NI, relu, flag, final_store);
    // rel 1: item -> user (dst=user)
    fused_gat_kernel<<<(NU + 3) / 4, 256, 0, stream>>>(
        xlI, xrU, rowptrU, srcU, att1, bias1, outU_dst, 0, NU, relu, flag, final_store);
  }
}

// Round 5
// 466.460 us; speedup vs baseline: 2.6892x; 1.3722x over previous
//
#include <hip/hip_runtime.h>

#define HDIM 128   // hidden = HEADS*D = 2*64

typedef __attribute__((ext_vector_type(8))) short short8;
typedef __attribute__((ext_vector_type(4))) float float4v;

__device__ __forceinline__ float b2f(unsigned short u){
  return __uint_as_float(((unsigned int)u) << 16);
}
__device__ __forceinline__ unsigned short f2b(float f){
  unsigned int x = __float_as_uint(f);
  x += 0x7fffu + ((x >> 16) & 1u);           // round-to-nearest-even
  return (unsigned short)(x >> 16);
}

// ---------------- dtype sniff: even-indexed ushorts of a bf16 buffer are values;
// of an fp32 buffer they are mantissa halves (~7% in-range). flag=1 -> fp32 inputs.
__global__ void detect_kernel(const unsigned short* __restrict__ x, int* __restrict__ flag){
  const int tid = threadIdx.x;               // single block of 256
  int cnt = 0, tot = 0;
  for (int i = tid * 2; i < 4096; i += 512){
    float v = fabsf(b2f(x[i]));
    tot++;
    if (v > 1e-4f && v < 50.f) cnt++;
  }
  __shared__ int s_cnt[256], s_tot[256];
  s_cnt[tid] = cnt; s_tot[tid] = tot;
  __syncthreads();
  for (int o = 128; o > 0; o >>= 1){
    if (tid < o){ s_cnt[tid] += s_cnt[tid + o]; s_tot[tid] += s_tot[tid + o]; }
    __syncthreads();
  }
  if (tid == 0) flag[0] = (s_cnt[0] * 2 < s_tot[0]) ? 1 : 0;
}

// canonical params layout (ushort offsets into P) — segments are CONTIGUOUS
#define P_WPU 0
#define P_WPI 8192
#define P_WL  24576
#define P_WR  90112
#define P_BL  155648
#define P_BR  156160
#define P_ATT 156672
#define P_BIA 157184
#define P_BPU 157696
#define P_BPI 157824
#define P_TOT 157952

struct CvtArgs { const void* src[10]; int len[10]; };

// one kernel converts all params into canonical bf16 P (dst index == t, contiguous)
__global__ void cvt_all_kernel(CvtArgs args, unsigned short* __restrict__ P,
                               const int* __restrict__ flag){
  int t = blockIdx.x * 256 + threadIdx.x;
  if (t >= P_TOT) return;
  int local = t;
  int i = 0;
  while (local >= args.len[i]){ local -= args.len[i]; i++; }
  if (*flag) P[t] = f2b(((const float*)args.src[i])[local]);
  else       P[t] = ((const unsigned short*)args.src[i])[local];
}

// ---------------- prep: compose layer-0 weights  Wc = Wp @ W  (+ bp @ W + b), bf16 out
// Wc layout: [0:8192) WpU@Wl00, [8192:16384) WpU@Wr01, [16384:32768) WpI@Wl01,
//            [32768:49152) WpI@Wr00, [49152:49664) 4x128 composed biases
__global__ void prep_weights_kernel(const unsigned short* __restrict__ P,
                                    unsigned short* __restrict__ Wc)
{
  const int t = blockIdx.x * 256 + threadIdx.x;
  if (t >= 49664) return;
  const unsigned short* Wl = P + P_WL;
  const unsigned short* Wr = P + P_WR;
  const unsigned short* Bm[4] = { Wl, Wr + 16384, Wl + 16384, Wr };
  const unsigned short* Av[4] = { P + P_WPU, P + P_WPU, P + P_WPI, P + P_WPI };
  const unsigned short* bv[4] = { P + P_BPU, P + P_BPU, P + P_BPI, P + P_BPI };
  const unsigned short* bo[4] = { P + P_BL, P + P_BR + 128, P + P_BL + 128, P + P_BR };
  if (t < 49152){
    int job, base;
    if (t < 8192)       { job = 0; base = 0; }
    else if (t < 16384) { job = 1; base = 8192; }
    else if (t < 32768) { job = 2; base = 16384; }
    else                { job = 3; base = 32768; }
    const int local = t - base;
    const int k = local >> 7, n = local & 127;
    const unsigned short* A = Av[job] + (size_t)k * 128;
    const unsigned short* B = Bm[job];
    float s = 0.f;
    #pragma unroll 4
    for (int h = 0; h < 128; h++) s = fmaf(b2f(A[h]), b2f(B[h * 128 + n]), s);
    Wc[t] = f2b(s);
  } else {
    const int local = t - 49152;
    const int job = local >> 7, n = local & 127;
    const unsigned short* B = Bm[job];
    float s = b2f(bo[job][n]);
    for (int h = 0; h < 128; h++) s = fmaf(b2f(bv[job][h]), b2f(B[h * 128 + n]), s);
    Wc[t] = f2b(s);
  }
}

// ---------------- permute concat weight [K][256] (cols<128 from W0, else W1) into
// B-fragment order: dst[((tile*KS+ks)*64+lane)*8+j] = W[ks*32+(lane>>4)*8+j][tile*16+(lane&15)]
__global__ void permute_w_kernel(const unsigned short* __restrict__ W0,
                                 const unsigned short* __restrict__ W1,
                                 unsigned short* __restrict__ dst, int KS, int n){
  int t = blockIdx.x * 256 + threadIdx.x;
  if (t >= n) return;
  int j = t & 7, rest = t >> 3;
  int l = rest & 63; rest >>= 6;
  int ks = rest % KS, tile = rest / KS;
  int k = ks * 32 + (l >> 4) * 8 + j;
  int c = tile * 16 + (l & 15);
  dst[t] = (c < 128) ? W0[k * 128 + c] : W1[k * 128 + (c - 128)];
}

// 4 concat bias sets [4][256]
__global__ void bias_cat_kernel(const unsigned short* a0, const unsigned short* b0,
                                const unsigned short* a1, const unsigned short* b1,
                                const unsigned short* a2, const unsigned short* b2,
                                const unsigned short* a3, const unsigned short* b3,
                                unsigned short* __restrict__ dst){
  int t = blockIdx.x * 256 + threadIdx.x;
  if (t >= 1024) return;
  const unsigned short* lo[4] = {a0, a1, a2, a3};
  const unsigned short* hi[4] = {b0, b1, b2, b3};
  int set = t >> 8, c = t & 255;
  dst[t] = (c < 128) ? lo[set][c] : hi[set][c - 128];
}

// ---------------- MFMA linear: Y[M,256] = X[M,K] @ Wcat[K,256] + bias, bf16 MFMA fp32 acc
// block: 4 waves; each wave: 64 rows x 64 cols (4 mtiles x 4 ntiles of 16x16x32 MFMA).
// A gathered from global (16B/lane), B from pre-permuted image (coalesced 16B/lane).
template<int K>
__launch_bounds__(256)
__global__ void linear_mfma_kernel(const void* __restrict__ Xv, int xstride,
                                   const int* __restrict__ flag, int use_flag,
                                   const unsigned short* __restrict__ Bp,
                                   const unsigned short* __restrict__ bias,
                                   unsigned short* __restrict__ Y, int M)
{
  constexpr int KS = K / 32;
  const int wave = threadIdx.x >> 6, lane = threadIdx.x & 63;
  const int quad = lane >> 4, l16 = lane & 15;
  const int row0 = blockIdx.x * 64;
  const bool f32 = use_flag && (*flag != 0);

  float4v acc[4][4];
  const float4v z = {0.f, 0.f, 0.f, 0.f};
  #pragma unroll
  for (int i = 0; i < 4; i++)
    #pragma unroll
    for (int j = 0; j < 4; j++) acc[i][j] = z;

  for (int ks = 0; ks < KS; ks++){
    const int col = ks * 32 + quad * 8;
    short8 a[4];
    #pragma unroll
    for (int mt = 0; mt < 4; mt++){
      int r = row0 + mt * 16 + l16; if (r >= M) r = M - 1;
      if (f32){
        const float* p = (const float*)Xv + (size_t)r * xstride + col;
        short8 tmp;
        #pragma unroll
        for (int j = 0; j < 8; j++) tmp[j] = (short)f2b(p[j]);
        a[mt] = tmp;
      } else {
        a[mt] = *(const short8*)((const unsigned short*)Xv + (size_t)r * xstride + col);
      }
    }
    short8 b[4];
    #pragma unroll
    for (int ntl = 0; ntl < 4; ntl++){
      const int t = wave * 4 + ntl;
      b[ntl] = *(const short8*)(Bp + ((size_t)(t * KS + ks) * 64 + lane) * 8);
    }
    #pragma unroll
    for (int mt = 0; mt < 4; mt++)
      #pragma unroll
      for (int ntl = 0; ntl < 4; ntl++)
        acc[mt][ntl] = __builtin_amdgcn_mfma_f32_16x16x32_bf16(a[mt], b[ntl], acc[mt][ntl], 0, 0, 0);
  }

  #pragma unroll
  for (int mt = 0; mt < 4; mt++){
    #pragma unroll
    for (int ntl = 0; ntl < 4; ntl++){
      const int t = wave * 4 + ntl;
      const int colb = t * 16 + l16;
      const float bb = b2f(bias[colb]);
      #pragma unroll
      for (int r = 0; r < 4; r++){
        const int row = row0 + mt * 16 + quad * 4 + r;
        if (row < M) Y[(size_t)row * 256 + colb] = f2b(acc[mt][ntl][r] + bb);
      }
    }
  }
}

// ================= CSR build =================
__global__ void count_kernel(const int* __restrict__ dst, int* __restrict__ deg, int E){
  int t = blockIdx.x * 256 + threadIdx.x;
  if (t < E) atomicAdd(&deg[dst[t]], 1);
}

__global__ void scan_block_kernel(const int* __restrict__ deg, int* __restrict__ rowptr,
                                  int* __restrict__ blksum, int Nd){
  __shared__ int s[256];
  const int tid = threadIdx.x;
  const int base = blockIdx.x * 2048 + tid * 8;
  int v[8]; int tot = 0;
  #pragma unroll
  for (int j = 0; j < 8; j++){
    int idx = base + j;
    v[j] = (idx < Nd) ? deg[idx] : 0;
    tot += v[j];
  }
  s[tid] = tot;
  __syncthreads();
  for (int off = 1; off < 256; off <<= 1){
    int add = (tid >= off) ? s[tid - off] : 0;
    __syncthreads();
    s[tid] += add;
    __syncthreads();
  }
  int run = s[tid] - tot;
  #pragma unroll
  for (int j = 0; j < 8; j++){
    int idx = base + j;
    if (idx < Nd) rowptr[idx] = run;
    run += v[j];
  }
  if (tid == 255) blksum[blockIdx.x] = s[255];
}

__global__ void scan_top_kernel(int* __restrict__ blksum, int B){
  const int tid = threadIdx.x;   // 64 threads
  int v = (tid < B) ? blksum[tid] : 0;
  const int orig = v;
  #pragma unroll
  for (int off = 1; off < 64; off <<= 1){
    int u = __shfl_up(v, off, 64);
    if (tid >= off) v += u;
  }
  if (tid < B) blksum[tid] = v - orig;
}

__global__ void scan_add_kernel(int* __restrict__ rowptr, const int* __restrict__ blksum,
                                int Nd, int E){
  const int base = blockIdx.x * 2048 + threadIdx.x * 8;
  const int add = blksum[blockIdx.x];
  #pragma unroll
  for (int j = 0; j < 8; j++){
    int idx = base + j;
    if (idx < Nd) rowptr[idx] += add;
    else if (idx == Nd) rowptr[idx] = E;
  }
}

__global__ void scatter_kernel(const int* __restrict__ dst, const int* __restrict__ src,
                               int* __restrict__ cursor, int* __restrict__ srcOut, int E){
  int t = blockIdx.x * 256 + threadIdx.x;
  if (t >= E) return;
  int d = dst[t];
  int pos = atomicAdd(&cursor[d], 1);
  srcOut[pos] = src[t];
}

// ================= fused per-destination GATv2 (online softmax) =================
// one wave per dst; lane holds features {2*lane, 2*lane+1}. xl/xr rows have
// stride 256 shorts (128 uints) inside the zlr buffers.
__launch_bounds__(256)
__global__ void fused_gat_kernel(const unsigned short* __restrict__ xl,
                                 const unsigned short* __restrict__ xr,
                                 const int* __restrict__ rowptr,
                                 const int* __restrict__ srcArr,
                                 const unsigned short* __restrict__ att,
                                 const unsigned short* __restrict__ bias,
                                 void* __restrict__ out, size_t elem_off,
                                 int Nd, int do_relu,
                                 const int* __restrict__ flag, int final_store)
{
  const int wave = threadIdx.x >> 6, lane = threadIdx.x & 63;
  const int d = blockIdx.x * 4 + wave;
  if (d >= Nd) return;

  const unsigned int rv = ((const unsigned int*)xr)[(size_t)d * 128 + lane];
  const float r0 = b2f((unsigned short)rv), r1 = b2f((unsigned short)(rv >> 16));
  const float a0 = b2f(att[2 * lane]), a1 = b2f(att[2 * lane + 1]);

  const int beg = rowptr[d], end = rowptr[d + 1];
  float m = -INFINITY, srun = 0.f, acc0 = 0.f, acc1 = 0.f;

  unsigned int xv = 0;
  if (beg < end) xv = ((const unsigned int*)xl)[(size_t)srcArr[beg] * 128 + lane];

  for (int e = beg; e < end; e++){
    const float x0 = b2f((unsigned short)xv), x1 = b2f((unsigned short)(xv >> 16));
    unsigned int xv_n = 0;
    if (e + 1 < end) xv_n = ((const unsigned int*)xl)[(size_t)srcArr[e + 1] * 128 + lane];

    float t0 = x0 + r0; t0 = fmaxf(t0, 0.2f * t0);     // leaky_relu 0.2
    float t1 = x1 + r1; t1 = fmaxf(t1, 0.2f * t1);
    float part = fmaf(a0, t0, a1 * t1);
    part += __shfl_xor(part, 1, 64);
    part += __shfl_xor(part, 2, 64);
    part += __shfl_xor(part, 4, 64);
    part += __shfl_xor(part, 8, 64);
    part += __shfl_xor(part, 16, 64);   // per-head (32-lane) sum
    const float mn = fmaxf(m, part);
    const float sc = __expf(m - mn);
    const float p  = __expf(part - mn);
    srun = fmaf(srun, sc, p);
    acc0 = fmaf(acc0, sc, p * x0);
    acc1 = fmaf(acc1, sc, p * x1);
    m = mn;
    xv = xv_n;
  }

  const float inv = 1.f / (srun + 1e-16f);
  float o0 = fmaf(acc0, inv, b2f(bias[2 * lane]));
  float o1 = fmaf(acc1, inv, b2f(bias[2 * lane + 1]));
  if (do_relu){ o0 = fmaxf(o0, 0.f); o1 = fmaxf(o1, 0.f); }
  const size_t idx = elem_off + (size_t)d * HDIM + 2 * lane;
  if (final_store && (*flag != 0)){
    ((float*)out)[idx] = o0;
    ((float*)out)[idx + 1] = o1;
  } else {
    ((unsigned int*)out)[idx >> 1] = (unsigned int)f2b(o0) | ((unsigned int)f2b(o1) << 16);
  }
}

extern "C" void kernel_launch(void* const* d_in, const int* in_sizes, int n_in,
                              void* d_out, int out_size, void* d_ws, size_t ws_size,
                              hipStream_t stream)
{
  const int* esrc = (const int*)d_in[12];
  const int* edst = (const int*)d_in[13];

  const int NU = in_sizes[0] / 64;    // 100000
  const int NI = in_sizes[1] / 128;   // 20000
  const int E  = in_sizes[12];        // 250000
  const size_t fu = (size_t)NU * HDIM, fi = (size_t)NI * HDIM;

  // ---- workspace carve (~66 MB), 256B-aligned regions
  char* w = (char*)d_ws;
  auto carve = [&](size_t bytes){ char* p = w; w += (bytes + 255) & ~(size_t)255; return p; };
  int* flag = (int*)carve(4);
  unsigned short* Wc = (unsigned short*)carve(49664 * 2);
  unsigned short* P  = (unsigned short*)carve((size_t)P_TOT * 2);
  unsigned short* BpU0 = (unsigned short*)carve(16384 * 2);   // K=64  permuted
  unsigned short* BpI0 = (unsigned short*)carve(32768 * 2);   // K=128
  unsigned short* BpU1 = (unsigned short*)carve(32768 * 2);
  unsigned short* BpI1 = (unsigned short*)carve(32768 * 2);
  unsigned short* Bc   = (unsigned short*)carve(1024 * 2);    // 4 concat biases
  int* rowptrI = (int*)carve(((size_t)NI + 1) * 4);
  int* rowptrU = (int*)carve(((size_t)NU + 1) * 4);
  int* cursI = (int*)carve((size_t)NI * 4);
  int* cursU = (int*)carve((size_t)NU * 4);
  int* blk   = (int*)carve(128 * 4);
  int* srcI  = (int*)carve((size_t)E * 4);
  int* srcU  = (int*)carve((size_t)E * 4);
  unsigned short* zlrU = (unsigned short*)carve((size_t)NU * 256 * 2);  // [NU][xl|xr]
  unsigned short* zlrI = (unsigned short*)carve((size_t)NI * 256 * 2);  // [NI][xl|xr]
  (void)ws_size; (void)n_in; (void)out_size;

  unsigned short* stage_zu = (unsigned short*)d_out;          // layer-0 bf16 staging
  unsigned short* stage_zi = (unsigned short*)d_out + fu;

  const int gE = (E + 255) / 256;

  // ---- dtype sniff + canonical bf16 params (single merged conversion)
  detect_kernel<<<1, 256, 0, stream>>>((const unsigned short*)d_in[0], flag);
  CvtArgs ca;
  const int srcIdx[10] = {2, 4, 6, 8, 7, 9, 10, 11, 3, 5};
  const int lens[10] = {8192, 16384, 65536, 65536, 512, 512, 512, 512, 128, 128};
  for (int i = 0; i < 10; i++){ ca.src[i] = d_in[srcIdx[i]]; ca.len[i] = lens[i]; }
  cvt_all_kernel<<<(P_TOT + 255) / 256, 256, 0, stream>>>(ca, P, flag);
  prep_weights_kernel<<<(49664 + 255) / 256, 256, 0, stream>>>(P, Wc);

  // composed layer-0 weights
  const unsigned short* cWlU0 = Wc;                 // [64,128]
  const unsigned short* cWrU1 = Wc + 8192;          // [64,128]
  const unsigned short* cWlI1 = Wc + 16384;         // [128,128]
  const unsigned short* cWrI0 = Wc + 32768;         // [128,128]

  // ---- B-fragment permuted weight images (xl cols 0-127, xr cols 128-255)
  permute_w_kernel<<<(16384 + 255) / 256, 256, 0, stream>>>(cWlU0, cWrU1, BpU0, 2, 16384);
  permute_w_kernel<<<(32768 + 255) / 256, 256, 0, stream>>>(cWlI1, cWrI0, BpI0, 4, 32768);
  permute_w_kernel<<<(32768 + 255) / 256, 256, 0, stream>>>(P + P_WL + 2 * 16384, P + P_WR + 3 * 16384, BpU1, 4, 32768);
  permute_w_kernel<<<(32768 + 255) / 256, 256, 0, stream>>>(P + P_WL + 3 * 16384, P + P_WR + 2 * 16384, BpI1, 4, 32768);
  bias_cat_kernel<<<4, 256, 0, stream>>>(
      Wc + 49152, Wc + 49152 + 128,            // U0: cb(l0 user xl) | cb(l0 user xr)
      Wc + 49152 + 256, Wc + 49152 + 384,      // I0
      P + P_BL + 256, P + P_BR + 384,          // U1: bl[1,0] | br[1,1]
      P + P_BL + 384, P + P_BR + 256,          // I1: bl[1,1] | br[1,0]
      Bc);

  // ---- CSR build, both directions (edges identical across layers)
  {
    const int B = (NI + 2047) / 2048;
    hipMemsetAsync(cursI, 0, (size_t)NI * 4, stream);
    count_kernel<<<gE, 256, 0, stream>>>(edst, cursI, E);
    scan_block_kernel<<<B, 256, 0, stream>>>(cursI, rowptrI, blk, NI);
    scan_top_kernel<<<1, 64, 0, stream>>>(blk, B);
    scan_add_kernel<<<B, 256, 0, stream>>>(rowptrI, blk, NI, E);
    hipMemcpyAsync(cursI, rowptrI, (size_t)NI * 4, hipMemcpyDeviceToDevice, stream);
    scatter_kernel<<<gE, 256, 0, stream>>>(edst, esrc, cursI, srcI, E);
  }
  {
    const int B = (NU + 2047) / 2048;
    hipMemsetAsync(cursU, 0, (size_t)NU * 4, stream);
    count_kernel<<<gE, 256, 0, stream>>>(esrc, cursU, E);
    scan_block_kernel<<<B, 256, 0, stream>>>(cursU, rowptrU, blk, NU);
    scan_top_kernel<<<1, 64, 0, stream>>>(blk, B);
    scan_add_kernel<<<B, 256, 0, stream>>>(rowptrU, blk, NU, E);
    hipMemcpyAsync(cursU, rowptrU, (size_t)NU * 4, hipMemcpyDeviceToDevice, stream);
    scatter_kernel<<<gE, 256, 0, stream>>>(esrc, edst, cursU, srcU, E);
  }

  const int gMU = (NU + 63) / 64, gMI = (NI + 63) / 64;

  for (int l = 0; l < 2; l++){
    if (l == 0){
      linear_mfma_kernel<64><<<gMU, 256, 0, stream>>>(d_in[0], 64, flag, 1, BpU0, Bc, zlrU, NU);
      linear_mfma_kernel<128><<<gMI, 256, 0, stream>>>(d_in[1], 128, flag, 1, BpI0, Bc + 256, zlrI, NI);
    } else {
      linear_mfma_kernel<128><<<gMU, 256, 0, stream>>>(stage_zu, 128, flag, 0, BpU1, Bc + 512, zlrU, NU);
      linear_mfma_kernel<128><<<gMI, 256, 0, stream>>>(stage_zi, 128, flag, 0, BpI1, Bc + 768, zlrI, NI);
    }
    const int relu = (l == 0);
    const int final_store = (l == 1);
    void* outI_dst = final_store ? d_out : (void*)stage_zu;  // zi at elem_off fu
    void* outU_dst = final_store ? d_out : (void*)stage_zu;  // zu at elem_off 0
    const unsigned short* att0  = P + P_ATT + (l * 2 + 0) * HDIM;
    const unsigned short* att1  = P + P_ATT + (l * 2 + 1) * HDIM;
    const unsigned short* bias0 = P + P_BIA + (l * 2 + 0) * HDIM;
    const unsigned short* bias1 = P + P_BIA + (l * 2 + 1) * HDIM;

    // rel 0: user -> item (dst=item): xl = user-xl (zlrU+0), xr = item-xr (zlrI+128)
    fused_gat_kernel<<<(NI + 3) / 4, 256, 0, stream>>>(
        zlrU, zlrI + 128, rowptrI, srcI, att0, bias0, outI_dst, fu, NI, relu, flag, final_store);
    // rel 1: item -> user (dst=user): xl = item-xl (zlrI+0), xr = user-xr (zlrU+128)
    fused_gat_kernel<<<(NU + 3) / 4, 256, 0, stream>>>(
        zlrI, zlrU + 128, rowptrU, srcU, att1, bias1, outU_dst, 0, NU, relu, flag, final_store);
  }
}

// Round 6
// 444.687 us; speedup vs baseline: 2.8209x; 1.0490x over previous
//
#include <hip/hip_runtime.h>

#define HDIM 128   // hidden = HEADS*D = 2*64

typedef __attribute__((ext_vector_type(8))) short short8;
typedef __attribute__((ext_vector_type(4))) float float4v;

__device__ __forceinline__ float b2f(unsigned short u){
  return __uint_as_float(((unsigned int)u) << 16);
}
__device__ __forceinline__ unsigned short f2b(float f){
  unsigned int x = __float_as_uint(f);
  x += 0x7fffu + ((x >> 16) & 1u);           // round-to-nearest-even
  return (unsigned short)(x >> 16);
}

// ---------------- dtype sniff: flag=1 -> fp32 inputs (see R3 post-mortem)
__global__ void detect_kernel(const unsigned short* __restrict__ x, int* __restrict__ flag){
  const int tid = threadIdx.x;               // single block of 256
  int cnt = 0, tot = 0;
  for (int i = tid * 2; i < 4096; i += 512){
    float v = fabsf(b2f(x[i]));
    tot++;
    if (v > 1e-4f && v < 50.f) cnt++;
  }
  __shared__ int s_cnt[256], s_tot[256];
  s_cnt[tid] = cnt; s_tot[tid] = tot;
  __syncthreads();
  for (int o = 128; o > 0; o >>= 1){
    if (tid < o){ s_cnt[tid] += s_cnt[tid + o]; s_tot[tid] += s_tot[tid + o]; }
    __syncthreads();
  }
  if (tid == 0) flag[0] = (s_cnt[0] * 2 < s_tot[0]) ? 1 : 0;
}

// canonical params layout (ushort offsets into P)
#define P_WPU 0
#define P_WPI 8192
#define P_WL  24576
#define P_WR  90112
#define P_BL  155648
#define P_BR  156160
#define P_ATT 156672
#define P_BIA 157184
#define P_BPU 157696
#define P_BPI 157824
#define P_TOT 157952

struct CvtArgs { const void* src[10]; int len[10]; };

__global__ void cvt_all_kernel(CvtArgs args, unsigned short* __restrict__ P,
                               const int* __restrict__ flag){
  int t = blockIdx.x * 256 + threadIdx.x;
  if (t >= P_TOT) return;
  int local = t;
  int i = 0;
  while (local >= args.len[i]){ local -= args.len[i]; i++; }
  if (*flag) P[t] = f2b(((const float*)args.src[i])[local]);
  else       P[t] = ((const unsigned short*)args.src[i])[local];
}

// ---------------- prep: compose layer-0 weights  Wc = Wp @ W  (+ bp @ W + b)
__global__ void prep_weights_kernel(const unsigned short* __restrict__ P,
                                    unsigned short* __restrict__ Wc)
{
  const int t = blockIdx.x * 256 + threadIdx.x;
  if (t >= 49664) return;
  const unsigned short* Wl = P + P_WL;
  const unsigned short* Wr = P + P_WR;
  const unsigned short* Bm[4] = { Wl, Wr + 16384, Wl + 16384, Wr };
  const unsigned short* Av[4] = { P + P_WPU, P + P_WPU, P + P_WPI, P + P_WPI };
  const unsigned short* bv[4] = { P + P_BPU, P + P_BPU, P + P_BPI, P + P_BPI };
  const unsigned short* bo[4] = { P + P_BL, P + P_BR + 128, P + P_BL + 128, P + P_BR };
  if (t < 49152){
    int job, base;
    if (t < 8192)       { job = 0; base = 0; }
    else if (t < 16384) { job = 1; base = 8192; }
    else if (t < 32768) { job = 2; base = 16384; }
    else                { job = 3; base = 32768; }
    const int local = t - base;
    const int k = local >> 7, n = local & 127;
    const unsigned short* A = Av[job] + (size_t)k * 128;
    const unsigned short* B = Bm[job];
    float s = 0.f;
    #pragma unroll 4
    for (int h = 0; h < 128; h++) s = fmaf(b2f(A[h]), b2f(B[h * 128 + n]), s);
    Wc[t] = f2b(s);
  } else {
    const int local = t - 49152;
    const int job = local >> 7, n = local & 127;
    const unsigned short* B = Bm[job];
    float s = b2f(bo[job][n]);
    for (int h = 0; h < 128; h++) s = fmaf(b2f(bv[job][h]), b2f(B[h * 128 + n]), s);
    Wc[t] = f2b(s);
  }
}

// ---------------- permute all 4 concat weights into B-fragment order, one launch
// dst[jobbase + ((tile*KS+ks)*64+l)*8+j] = W[ks*32+(l>>4)*8+j][tile*16+(l&15)]
struct PermArgs { const unsigned short* W0[4]; const unsigned short* W1[4];
                  int KS[4]; int base[4]; int n[4]; };
__global__ void permute_all_kernel(PermArgs pa, unsigned short* __restrict__ dst){
  int t = blockIdx.x * 256 + threadIdx.x;
  int job = 0;
  while (job < 4 && t >= pa.base[job] + pa.n[job]) job++;
  if (job >= 4) return;
  int local = t - pa.base[job];
  int KS = pa.KS[job];
  int j = local & 7, rest = local >> 3;
  int l = rest & 63; rest >>= 6;
  int ks = rest % KS, tile = rest / KS;
  int k = ks * 32 + (l >> 4) * 8 + j;
  int c = tile * 16 + (l & 15);
  dst[t] = (c < 128) ? pa.W0[job][k * 128 + c] : pa.W1[job][k * 128 + (c - 128)];
}

// 4 concat bias sets [4][256]
__global__ void bias_cat_kernel(const unsigned short* a0, const unsigned short* b0,
                                const unsigned short* a1, const unsigned short* b1,
                                const unsigned short* a2, const unsigned short* b2,
                                const unsigned short* a3, const unsigned short* b3,
                                unsigned short* __restrict__ dst){
  int t = blockIdx.x * 256 + threadIdx.x;
  if (t >= 1024) return;
  const unsigned short* lo[4] = {a0, a1, a2, a3};
  const unsigned short* hi[4] = {b0, b1, b2, b3};
  int set = t >> 8, c = t & 255;
  dst[t] = (c < 128) ? lo[set][c] : hi[set][c - 128];
}

// ---------------- MFMA linear: Y[M,256] = X[M,K] @ Wcat[K,256] + bias (unchanged from R5)
template<int K>
__launch_bounds__(256)
__global__ void linear_mfma_kernel(const void* __restrict__ Xv, int xstride,
                                   const int* __restrict__ flag, int use_flag,
                                   const unsigned short* __restrict__ Bp,
                                   const unsigned short* __restrict__ bias,
                                   unsigned short* __restrict__ Y, int M)
{
  constexpr int KS = K / 32;
  const int wave = threadIdx.x >> 6, lane = threadIdx.x & 63;
  const int quad = lane >> 4, l16 = lane & 15;
  const int row0 = blockIdx.x * 64;
  const bool f32 = use_flag && (*flag != 0);

  float4v acc[4][4];
  const float4v z = {0.f, 0.f, 0.f, 0.f};
  #pragma unroll
  for (int i = 0; i < 4; i++)
    #pragma unroll
    for (int j = 0; j < 4; j++) acc[i][j] = z;

  for (int ks = 0; ks < KS; ks++){
    const int col = ks * 32 + quad * 8;
    short8 a[4];
    #pragma unroll
    for (int mt = 0; mt < 4; mt++){
      int r = row0 + mt * 16 + l16; if (r >= M) r = M - 1;
      if (f32){
        const float* p = (const float*)Xv + (size_t)r * xstride + col;
        short8 tmp;
        #pragma unroll
        for (int j = 0; j < 8; j++) tmp[j] = (short)f2b(p[j]);
        a[mt] = tmp;
      } else {
        a[mt] = *(const short8*)((const unsigned short*)Xv + (size_t)r * xstride + col);
      }
    }
    short8 b[4];
    #pragma unroll
    for (int ntl = 0; ntl < 4; ntl++){
      const int t = wave * 4 + ntl;
      b[ntl] = *(const short8*)(Bp + ((size_t)(t * KS + ks) * 64 + lane) * 8);
    }
    #pragma unroll
    for (int mt = 0; mt < 4; mt++)
      #pragma unroll
      for (int ntl = 0; ntl < 4; ntl++)
        acc[mt][ntl] = __builtin_amdgcn_mfma_f32_16x16x32_bf16(a[mt], b[ntl], acc[mt][ntl], 0, 0, 0);
  }

  #pragma unroll
  for (int mt = 0; mt < 4; mt++){
    #pragma unroll
    for (int ntl = 0; ntl < 4; ntl++){
      const int t = wave * 4 + ntl;
      const int colb = t * 16 + l16;
      const float bb = b2f(bias[colb]);
      #pragma unroll
      for (int r = 0; r < 4; r++){
        const int row = row0 + mt * 16 + quad * 4 + r;
        if (row < M) Y[(size_t)row * 256 + colb] = f2b(acc[mt][ntl][r] + bb);
      }
    }
  }
}

// ================= CSR build (consolidated) =================
__global__ void count_both_kernel(const int* __restrict__ esrc, const int* __restrict__ edst,
                                  int* __restrict__ degU, int* __restrict__ degI, int E){
  int t = blockIdx.x * 256 + threadIdx.x;
  if (t >= E) return;
  atomicAdd(&degI[edst[t]], 1);
  atomicAdd(&degU[esrc[t]], 1);
}

// partitioned per-block scan: blocks [0,BI) -> item arrays, [BI,BI+BU) -> user
__global__ void scan_block2_kernel(const int* __restrict__ degI, const int* __restrict__ degU,
                                   int* __restrict__ rpI, int* __restrict__ rpU,
                                   int* __restrict__ blkI, int* __restrict__ blkU,
                                   int NI, int NU, int BI){
  __shared__ int s[256];
  const int tid = threadIdx.x;
  const int b = blockIdx.x;
  const int* deg; int* rowptr; int* blksum; int Nd; int bb;
  if (b < BI){ deg = degI; rowptr = rpI; blksum = blkI; Nd = NI; bb = b; }
  else       { deg = degU; rowptr = rpU; blksum = blkU; Nd = NU; bb = b - BI; }
  const int base = bb * 2048 + tid * 8;
  int v[8]; int tot = 0;
  #pragma unroll
  for (int j = 0; j < 8; j++){
    int idx = base + j;
    v[j] = (idx < Nd) ? deg[idx] : 0;
    tot += v[j];
  }
  s[tid] = tot;
  __syncthreads();
  for (int off = 1; off < 256; off <<= 1){
    int add = (tid >= off) ? s[tid - off] : 0;
    __syncthreads();
    s[tid] += add;
    __syncthreads();
  }
  int run = s[tid] - tot;
  #pragma unroll
  for (int j = 0; j < 8; j++){
    int idx = base + j;
    if (idx < Nd) rowptr[idx] = run;
    run += v[j];
  }
  if (tid == 255) blksum[bb] = s[255];
}

// two waves: wave0 scans blkI (BI<=64), wave1 scans blkU (BU<=64)
__global__ void scan_top2_kernel(int* __restrict__ blkI, int BI,
                                 int* __restrict__ blkU, int BU){
  const int tid = threadIdx.x;   // 128 threads
  int* blk = (tid < 64) ? blkI : blkU;
  const int B = (tid < 64) ? BI : BU;
  const int lane = tid & 63;
  int v = (lane < B) ? blk[lane] : 0;
  const int orig = v;
  #pragma unroll
  for (int off = 1; off < 64; off <<= 1){
    int u = __shfl_up(v, off, 64);
    if (lane >= off) v += u;
  }
  if (lane < B) blk[lane] = v - orig;
}

// add block offsets; write cursor copy; set rowptr[Nd]=E
__global__ void scan_add2_kernel(int* __restrict__ rpI, int* __restrict__ rpU,
                                 const int* __restrict__ blkI, const int* __restrict__ blkU,
                                 int* __restrict__ curI, int* __restrict__ curU,
                                 int NI, int NU, int BI, int E){
  const int b = blockIdx.x;
  int* rowptr; const int* blksum; int* curs; int Nd; int bb;
  if (b < BI){ rowptr = rpI; blksum = blkI; curs = curI; Nd = NI; bb = b; }
  else       { rowptr = rpU; blksum = blkU; curs = curU; Nd = NU; bb = b - BI; }
  const int base = bb * 2048 + threadIdx.x * 8;
  const int add = blksum[bb];
  #pragma unroll
  for (int j = 0; j < 8; j++){
    int idx = base + j;
    if (idx < Nd){ int v = rowptr[idx] + add; rowptr[idx] = v; curs[idx] = v; }
    else if (idx == Nd) rowptr[idx] = E;
  }
}

__global__ void scatter_both_kernel(const int* __restrict__ esrc, const int* __restrict__ edst,
                                    int* __restrict__ curI, int* __restrict__ curU,
                                    int* __restrict__ srcI, int* __restrict__ srcU, int E){
  int t = blockIdx.x * 256 + threadIdx.x;
  if (t < E){
    int d = edst[t];
    int pos = atomicAdd(&curI[d], 1);
    srcI[pos] = esrc[t];
  } else if (t < 2 * E){
    int tt = t - E;
    int d = esrc[tt];
    int pos = atomicAdd(&curU[d], 1);
    srcU[pos] = edst[tt];
  }
}

// ================= dual-relation fused GATv2, online softmax, unroll-2 =================
struct GatRel {
  const unsigned short* xl;   // [N][256] bf16, xl at +0
  const unsigned short* xr;   // [N][256] bf16, xr half (pass base+128)
  const int* rowptr;
  const int* srcArr;
  const unsigned short* att;  // [256] (128 used)
  const unsigned short* bias;
  void* out;
  unsigned long long elem_off;
  int Nd;
};

__launch_bounds__(1024)
__global__ void fused_gat_dual_kernel(GatRel A, GatRel B, int do_relu,
                                      const int* __restrict__ flag, int final_store)
{
  const int wave = threadIdx.x >> 6, lane = threadIdx.x & 63;
  int g = blockIdx.x * 16 + wave;
  GatRel R;
  int d;
  if (g < A.Nd){ R = A; d = g; }
  else {
    g -= A.Nd;
    if (g >= B.Nd) return;
    R = B; d = g;
  }

  const unsigned int rv = ((const unsigned int*)R.xr)[(size_t)d * 128 + lane];
  const float r0 = b2f((unsigned short)rv), r1 = b2f((unsigned short)(rv >> 16));
  const float a0 = b2f(R.att[2 * lane]), a1 = b2f(R.att[2 * lane + 1]);

  const int beg = R.rowptr[d], end = R.rowptr[d + 1];
  float m = -INFINITY, srun = 0.f, acc0 = 0.f, acc1 = 0.f;

  const unsigned int* xlv = (const unsigned int*)R.xl;
  int e = beg;
  unsigned int c0 = 0, c1 = 0;
  if (e < end)     c0 = xlv[(size_t)R.srcArr[e] * 128 + lane];
  if (e + 1 < end) c1 = xlv[(size_t)R.srcArr[e + 1] * 128 + lane];

  while (e < end){
    const int e2 = e + 2;
    unsigned int n0 = 0, n1 = 0;
    if (e2 < end)     n0 = xlv[(size_t)R.srcArr[e2] * 128 + lane];
    if (e2 + 1 < end) n1 = xlv[(size_t)R.srcArr[e2 + 1] * 128 + lane];
    const bool has1 = (e + 1 < end);

    const float x00 = b2f((unsigned short)c0), x01 = b2f((unsigned short)(c0 >> 16));
    const float x10 = b2f((unsigned short)c1), x11 = b2f((unsigned short)(c1 >> 16));
    float t00 = x00 + r0; t00 = fmaxf(t00, 0.2f * t00);
    float t01 = x01 + r1; t01 = fmaxf(t01, 0.2f * t01);
    float t10 = x10 + r0; t10 = fmaxf(t10, 0.2f * t10);
    float t11 = x11 + r1; t11 = fmaxf(t11, 0.2f * t11);
    float p0 = fmaf(a0, t00, a1 * t01);
    float p1 = fmaf(a0, t10, a1 * t11);
    // two interleaved per-head (32-lane) reductions — ILP 2
    #pragma unroll
    for (int k = 1; k <= 16; k <<= 1){
      p0 += __shfl_xor(p0, k, 64);
      p1 += __shfl_xor(p1, k, 64);
    }
    if (!has1) p1 = -INFINITY;
    // pairwise merge, then merge into running state
    const float m2 = fmaxf(p0, p1);
    const float q0 = __expf(p0 - m2);
    const float q1 = has1 ? __expf(p1 - m2) : 0.f;
    const float s2 = q0 + q1;
    const float b0 = fmaf(q0, x00, q1 * x10);
    const float b1 = fmaf(q0, x01, q1 * x11);
    const float mn = fmaxf(m, m2);
    const float scO = __expf(m - mn);     // first iter: exp(-inf)=0
    const float sc2 = __expf(m2 - mn);
    srun = fmaf(srun, scO, s2 * sc2);
    acc0 = fmaf(acc0, scO, b0 * sc2);
    acc1 = fmaf(acc1, scO, b1 * sc2);
    m = mn;
    c0 = n0; c1 = n1;
    e = e2;
  }

  const float inv = 1.f / (srun + 1e-16f);
  float o0 = fmaf(acc0, inv, b2f(R.bias[2 * lane]));
  float o1 = fmaf(acc1, inv, b2f(R.bias[2 * lane + 1]));
  if (do_relu){ o0 = fmaxf(o0, 0.f); o1 = fmaxf(o1, 0.f); }
  const size_t idx = (size_t)R.elem_off + (size_t)d * HDIM + 2 * lane;   // even
  if (final_store && (*flag != 0)){
    float2 o; o.x = o0; o.y = o1;
    ((float2*)R.out)[idx >> 1] = o;
  } else {
    ((unsigned int*)R.out)[idx >> 1] = (unsigned int)f2b(o0) | ((unsigned int)f2b(o1) << 16);
  }
}

extern "C" void kernel_launch(void* const* d_in, const int* in_sizes, int n_in,
                              void* d_out, int out_size, void* d_ws, size_t ws_size,
                              hipStream_t stream)
{
  const int* esrc = (const int*)d_in[12];
  const int* edst = (const int*)d_in[13];

  const int NU = in_sizes[0] / 64;    // 100000
  const int NI = in_sizes[1] / 128;   // 20000
  const int E  = in_sizes[12];        // 250000
  const size_t fu = (size_t)NU * HDIM, fi = (size_t)NI * HDIM;

  // ---- workspace carve, 256B-aligned regions
  char* w = (char*)d_ws;
  auto carve = [&](size_t bytes){ char* p = w; w += (bytes + 255) & ~(size_t)255; return p; };
  int* flag = (int*)carve(4);
  unsigned short* Wc = (unsigned short*)carve(49664 * 2);
  unsigned short* P  = (unsigned short*)carve((size_t)P_TOT * 2);
  unsigned short* Bp = (unsigned short*)carve(114688 * 2);   // 4 permuted weight images
  unsigned short* Bc = (unsigned short*)carve(1024 * 2);     // 4 concat biases
  int* rowptrI = (int*)carve(((size_t)NI + 1) * 4);
  int* rowptrU = (int*)carve(((size_t)NU + 1) * 4);
  int* curs    = (int*)carve(((size_t)NI + NU) * 4);         // [cursI | cursU] contiguous
  int* cursI = curs;
  int* cursU = curs + NI;
  int* blkI = (int*)carve(64 * 4);
  int* blkU = (int*)carve(64 * 4);
  int* srcI  = (int*)carve((size_t)E * 4);
  int* srcU  = (int*)carve((size_t)E * 4);
  unsigned short* zlrU = (unsigned short*)carve((size_t)NU * 256 * 2);  // [NU][xl|xr]
  unsigned short* zlrI = (unsigned short*)carve((size_t)NI * 256 * 2);  // [NI][xl|xr]
  (void)ws_size; (void)n_in; (void)out_size;

  unsigned short* stage_zu = (unsigned short*)d_out;          // layer-0 bf16 staging
  unsigned short* stage_zi = (unsigned short*)d_out + fu;

  // ---- dtype sniff + canonical bf16 params
  detect_kernel<<<1, 256, 0, stream>>>((const unsigned short*)d_in[0], flag);
  CvtArgs ca;
  const int srcIdx[10] = {2, 4, 6, 8, 7, 9, 10, 11, 3, 5};
  const int lens[10] = {8192, 16384, 65536, 65536, 512, 512, 512, 512, 128, 128};
  for (int i = 0; i < 10; i++){ ca.src[i] = d_in[srcIdx[i]]; ca.len[i] = lens[i]; }
  cvt_all_kernel<<<(P_TOT + 255) / 256, 256, 0, stream>>>(ca, P, flag);
  prep_weights_kernel<<<(49664 + 255) / 256, 256, 0, stream>>>(P, Wc);

  const unsigned short* cWlU0 = Wc;                 // [64,128]
  const unsigned short* cWrU1 = Wc + 8192;          // [64,128]
  const unsigned short* cWlI1 = Wc + 16384;         // [128,128]
  const unsigned short* cWrI0 = Wc + 32768;         // [128,128]

  // ---- permuted B-images (one launch) + concat biases
  PermArgs pa;
  pa.W0[0] = cWlU0;                 pa.W1[0] = cWrU1;                 pa.KS[0] = 2; pa.base[0] = 0;     pa.n[0] = 16384;
  pa.W0[1] = cWlI1;                 pa.W1[1] = cWrI0;                 pa.KS[1] = 4; pa.base[1] = 16384; pa.n[1] = 32768;
  pa.W0[2] = P + P_WL + 2 * 16384;  pa.W1[2] = P + P_WR + 3 * 16384;  pa.KS[2] = 4; pa.base[2] = 49152; pa.n[2] = 32768;
  pa.W0[3] = P + P_WL + 3 * 16384;  pa.W1[3] = P + P_WR + 2 * 16384;  pa.KS[3] = 4; pa.base[3] = 81920; pa.n[3] = 32768;
  permute_all_kernel<<<(114688 + 255) / 256, 256, 0, stream>>>(pa, Bp);
  unsigned short* BpU0 = Bp;
  unsigned short* BpI0 = Bp + 16384;
  unsigned short* BpU1 = Bp + 49152;
  unsigned short* BpI1 = Bp + 81920;
  bias_cat_kernel<<<4, 256, 0, stream>>>(
      Wc + 49152, Wc + 49152 + 128,
      Wc + 49152 + 256, Wc + 49152 + 384,
      P + P_BL + 256, P + P_BR + 384,
      P + P_BL + 384, P + P_BR + 256,
      Bc);

  // ---- CSR build, both directions, 6 dispatches
  const int BI = (NI + 2047) / 2048, BU = (NU + 2047) / 2048;
  hipMemsetAsync(curs, 0, ((size_t)NI + NU) * 4, stream);
  count_both_kernel<<<(E + 255) / 256, 256, 0, stream>>>(esrc, edst, cursU, cursI, E);
  scan_block2_kernel<<<BI + BU, 256, 0, stream>>>(cursI, cursU, rowptrI, rowptrU, blkI, blkU, NI, NU, BI);
  scan_top2_kernel<<<1, 128, 0, stream>>>(blkI, BI, blkU, BU);
  scan_add2_kernel<<<BI + BU, 256, 0, stream>>>(rowptrI, rowptrU, blkI, blkU, cursI, cursU, NI, NU, BI, E);
  scatter_both_kernel<<<(2 * E + 255) / 256, 256, 0, stream>>>(esrc, edst, cursI, cursU, srcI, srcU, E);

  const int gMU = (NU + 63) / 64, gMI = (NI + 63) / 64;

  for (int l = 0; l < 2; l++){
    if (l == 0){
      linear_mfma_kernel<64><<<gMU, 256, 0, stream>>>(d_in[0], 64, flag, 1, BpU0, Bc, zlrU, NU);
      linear_mfma_kernel<128><<<gMI, 256, 0, stream>>>(d_in[1], 128, flag, 1, BpI0, Bc + 256, zlrI, NI);
    } else {
      linear_mfma_kernel<128><<<gMU, 256, 0, stream>>>(stage_zu, 128, flag, 0, BpU1, Bc + 512, zlrU, NU);
      linear_mfma_kernel<128><<<gMI, 256, 0, stream>>>(stage_zi, 128, flag, 0, BpI1, Bc + 768, zlrI, NI);
    }
    const int relu = (l == 0);
    const int final_store = (l == 1);

    GatRel A, B;
    // rel 0: user -> item (dst=item): xl = user-xl, xr = item-xr
    A.xl = zlrU; A.xr = zlrI + 128; A.rowptr = rowptrI; A.srcArr = srcI;
    A.att  = P + P_ATT + (l * 2 + 0) * HDIM;
    A.bias = P + P_BIA + (l * 2 + 0) * HDIM;
    A.out = final_store ? d_out : (void*)stage_zu; A.elem_off = fu; A.Nd = NI;
    // rel 1: item -> user (dst=user): xl = item-xl, xr = user-xr
    B.xl = zlrI; B.xr = zlrU + 128; B.rowptr = rowptrU; B.srcArr = srcU;
    B.att  = P + P_ATT + (l * 2 + 1) * HDIM;
    B.bias = P + P_BIA + (l * 2 + 1) * HDIM;
    B.out = final_store ? d_out : (void*)stage_zu; B.elem_off = 0; B.Nd = NU;

    fused_gat_dual_kernel<<<(NI + NU + 15) / 16, 1024, 0, stream>>>(A, B, relu, flag, final_store);
  }
}